// Round 5
// baseline (261.929 us; speedup 1.0000x reference)
//
#include <hip/hip_runtime.h>
#include <hip/hip_bf16.h>

// MultiHeadAttention S=1024 B=4 D=1024 H=16 DH=64
// [0] transpose_w: Wq/Wk/Wv/Wo f32 -> bf16 B^T[n][k] (one-time)
// [1] qkv_gemm: 128x128 tile GEMM; q output pre-scaled by log2(e)/8.
//     Grid is (row, col, proj) with row FASTEST so the 8 col-tiles sharing an
//     A row-strip land on the SAME XCD (flat%8 == row%8) -> A re-reads hit L2.
// [2] attn: flash-style, LDS double-buffered, mask via accumulator-init bias.
// [3] out_gemm (same swizzle).
// ws (bf16 elems): q @0, k @NE, v @2NE, attn_out @3NE, WT(4x1M) @4NE (40MB)

typedef __attribute__((ext_vector_type(8))) short short8;
typedef __attribute__((ext_vector_type(4))) short short4_;
typedef __attribute__((ext_vector_type(4))) float f32x4;
typedef __attribute__((ext_vector_type(16))) float f32x16;
typedef __attribute__((ext_vector_type(8))) __bf16 bf16x8;
typedef __attribute__((ext_vector_type(4))) __bf16 bf16x4;

union B8 {
    short8 s;
    bf16x8 b;
    unsigned short u[8];
};
union B4 {
    short4_ s;
    bf16x4 b;
    unsigned short u[4];
    int i[2];
};

#if __has_builtin(__builtin_amdgcn_exp2f)
#define EXP2(x) __builtin_amdgcn_exp2f(x)
#else
#define EXP2(x) exp2f(x)
#endif
#if __has_builtin(__builtin_amdgcn_rcpf)
#define RCP(x) __builtin_amdgcn_rcpf(x)
#else
#define RCP(x) (1.0f / (x))
#endif

static __device__ __forceinline__ unsigned short f2bf_rne(float f) {
    union { float f; unsigned u; } v; v.f = f;
    unsigned r = v.u + 0x7FFFu + ((v.u >> 16) & 1u);
    return (unsigned short)(r >> 16);
}

static __device__ __forceinline__ void async_lds16(const void* g, const void* l) {
    __builtin_amdgcn_global_load_lds(
        (const __attribute__((address_space(1))) unsigned int*)(unsigned long long)g,
        (__attribute__((address_space(3))) unsigned int*)(unsigned int)(unsigned long long)l,
        16, 0, 0);
}

// ---------------------------------------------------------------------------
// One-time weight transpose+convert: dst[n][k] = bf16(src[k][n]).
// ---------------------------------------------------------------------------
__global__ __launch_bounds__(256) void transpose_w(
    const float* __restrict__ Wq, const float* __restrict__ Wk,
    const float* __restrict__ Wv, const float* __restrict__ Wo,
    unsigned short* __restrict__ WT) {
    __shared__ float sT[64][65];
    const int t = threadIdx.x;
    const int dtile = blockIdx.x;
    const int sub = blockIdx.y;
    const int z = blockIdx.z;

    const float* src;
    int spitch;
    unsigned short* dst;
    if (z < 3) {
        const float* W = (z == 0) ? Wq : (z == 1) ? Wk : Wv;
        src = W + (size_t)sub * 65536 + (size_t)dtile * 64 * 64;
        spitch = 64;
        dst = WT + (size_t)z * 1048576 + (size_t)(sub * 64) * 1024 + dtile * 64;
    } else {
        src = Wo + (size_t)dtile * 64 * 1024 + sub * 64;
        spitch = 1024;
        dst = WT + (size_t)3 * 1048576 + (size_t)(sub * 64) * 1024 + dtile * 64;
    }

    const int r = t >> 2;
    const int cseg = (t & 3) * 16;
#pragma unroll
    for (int i = 0; i < 4; ++i) {
        f32x4 v = *(const f32x4*)(src + (size_t)r * spitch + cseg + i * 4);
#pragma unroll
        for (int j = 0; j < 4; ++j) sT[r][cseg + i * 4 + j] = v[j];
    }
    __syncthreads();
    B8 w0, w1;
#pragma unroll
    for (int i = 0; i < 8; ++i) {
        w0.u[i] = f2bf_rne(sT[cseg + i][r]);
        w1.u[i] = f2bf_rne(sT[cseg + 8 + i][r]);
    }
    *(short8*)(dst + (size_t)r * 1024 + cseg) = w0.s;
    *(short8*)(dst + (size_t)r * 1024 + cseg + 8) = w1.s;
}

// ---------------------------------------------------------------------------
// 128x128-tile GEMM (BK=64) with output scale.
// blockIdx.x = row-tile (fastest -> XCD pinning), blockIdx.y = col-tile.
// ---------------------------------------------------------------------------
template <bool A_F32, bool OUT_F32>
__device__ __forceinline__ void gemm128(const void* __restrict__ Av,
                                        const unsigned short* __restrict__ Bt,
                                        const float* __restrict__ bias,
                                        void* __restrict__ Cv, float oscale) {
    __shared__ unsigned short sA[128 * 64];
    __shared__ unsigned short sB[128 * 64];
    const int t = threadIdx.x;
    const int w = t >> 6;
    const int lane = t & 63;
    const int quad = lane >> 4;
    const int l15 = lane & 15;
    const int wr = w >> 1;
    const int wc = w & 1;
    const int row0 = blockIdx.x * 128;  // row fastest: same-A blocks -> same XCD
    const int col0 = blockIdx.y * 128;
    const int lrow8 = lane >> 3;
    const int lseg = lane & 7;

    f32x4 acc[4][4] = {};

    for (int k0 = 0; k0 < 1024; k0 += 64) {
#pragma unroll
        for (int i = 0; i < 4; ++i) {
            const int rr = w * 32 + i * 8;
            async_lds16(Bt + (size_t)(col0 + rr + lrow8) * 1024 + k0 + lseg * 8,
                        &sB[rr * 64]);
        }
        if constexpr (A_F32) {
            const float* A = (const float*)Av;
#pragma unroll
            for (int i = 0; i < 4; ++i) {
                const int rr = w * 32 + i * 8 + lrow8;
                const float* src = A + (size_t)(row0 + rr) * 1024 + k0 + lseg * 8;
                f32x4 v0 = *(const f32x4*)src;
                f32x4 v1 = *(const f32x4*)(src + 4);
                B8 pk;
#pragma unroll
                for (int j = 0; j < 4; ++j) {
                    pk.u[j] = f2bf_rne(v0[j]);
                    pk.u[4 + j] = f2bf_rne(v1[j]);
                }
                *(short8*)&sA[rr * 64 + lseg * 8] = pk.s;
            }
        } else {
            const unsigned short* A = (const unsigned short*)Av;
#pragma unroll
            for (int i = 0; i < 4; ++i) {
                const int rr = w * 32 + i * 8;
                async_lds16(A + (size_t)(row0 + rr + lrow8) * 1024 + k0 + lseg * 8,
                            &sA[rr * 64]);
            }
        }
        __syncthreads();
#pragma unroll
        for (int kf = 0; kf < 2; ++kf) {
            B8 af[4], bf[4];
#pragma unroll
            for (int i = 0; i < 4; ++i)
                af[i].s = *(const short8*)&sA[(wr * 64 + i * 16 + l15) * 64 + kf * 32 + quad * 8];
#pragma unroll
            for (int j = 0; j < 4; ++j)
                bf[j].s = *(const short8*)&sB[(wc * 64 + j * 16 + l15) * 64 + kf * 32 + quad * 8];
#pragma unroll
            for (int i = 0; i < 4; ++i)
#pragma unroll
                for (int j = 0; j < 4; ++j)
                    acc[i][j] = __builtin_amdgcn_mfma_f32_16x16x32_bf16(af[i].b, bf[j].b,
                                                                        acc[i][j], 0, 0, 0);
        }
        __syncthreads();
    }
#pragma unroll
    for (int j = 0; j < 4; ++j) {
        const int col = col0 + wc * 64 + j * 16 + l15;
        const float bb = bias[col];
#pragma unroll
        for (int i = 0; i < 4; ++i) {
#pragma unroll
            for (int r = 0; r < 4; ++r) {
                const int row = row0 + wr * 64 + i * 16 + quad * 4 + r;
                const size_t idx = (size_t)row * 1024 + col;
                const float val = (acc[i][j][r] + bb) * oscale;
                if constexpr (OUT_F32)
                    ((float*)Cv)[idx] = val;
                else
                    ((unsigned short*)Cv)[idx] = f2bf_rne(val);
            }
        }
    }
}

#define SCALE_L2E 0.18033688011112042f  // (1/8) * log2(e)

__global__ __launch_bounds__(256) void qkv_gemm(
    const float* __restrict__ Q, const float* __restrict__ Kx, const float* __restrict__ Vx,
    const unsigned short* __restrict__ WT,
    const float* __restrict__ bq, const float* __restrict__ bk, const float* __restrict__ bv,
    unsigned short* q_o, unsigned short* k_o, unsigned short* v_o) {
    const int p = blockIdx.z;
    const float* A = (p == 0) ? Q : (p == 1) ? Kx : Vx;
    const unsigned short* Bt = WT + (size_t)p * 1048576;
    const float* bias = (p == 0) ? bq : (p == 1) ? bk : bv;
    unsigned short* C = (p == 0) ? q_o : (p == 1) ? k_o : v_o;
    const float osc = (p == 0) ? SCALE_L2E : 1.0f;  // pre-scale q for attn exp2
    gemm128<true, false>(A, Bt, bias, C, osc);
}

__global__ __launch_bounds__(256) void out_gemm(const unsigned short* __restrict__ A,
                                                const unsigned short* __restrict__ WT,
                                                const float* __restrict__ bo,
                                                float* __restrict__ C) {
    gemm128<false, true>(A, WT + (size_t)3 * 1048576, bo, C, 1.0f);
}

// ---------------------------------------------------------------------------
// Flash-style attention, double-buffered LDS, 1 sync per k-tile.
// ---------------------------------------------------------------------------
#define TP 72

#if __has_builtin(__builtin_amdgcn_mfma_f32_32x32x8bf16_1k)
#define HAVE_X8 1
#endif

__global__ __launch_bounds__(256) void attn_kernel(
    const unsigned short* __restrict__ q,   // pre-scaled by log2(e)/8
    const unsigned short* __restrict__ k,
    const unsigned short* __restrict__ v,
    const int* __restrict__ key_mask,
    unsigned short* __restrict__ o) {
    __shared__ unsigned short sK[2][64 * TP];
    __shared__ unsigned short sVt[2][64 * TP];
    __shared__ float sBias[2048];  // [kt][blk][hh][r]
    __shared__ unsigned long long sBits[16];

    const int t = threadIdx.x;
    const int wave = t >> 6;
    const int lane = t & 63;
    const int n31 = lane & 31;
    const int hh = lane >> 5;
    const int b = blockIdx.y;
    const int h = blockIdx.z;
    const int q0w = blockIdx.x * 128 + wave * 32;
    const int srow = t >> 3;  // 0..31
    const int sseg = t & 7;   // 0..7

    // mask bits: bit set => masked out
#pragma unroll
    for (int i = 0; i < 4; ++i) {
        const int idx = i * 4 + wave;
        const int sk = idx * 64 + lane;
        unsigned long long bal = __ballot(key_mask[sk * 4 + b] != 0);
        if (lane == 0) sBits[idx] = bal;
    }
    __syncthreads();
    // accumulator-init bias table: -16384 => exp2 underflow => exact 0
#pragma unroll
    for (int i = 0; i < 8; ++i) {
        const int idx = t * 8 + i;
        const int r = idx & 15;
        const int hb = (idx >> 4) & 1;
        const int blk = (idx >> 5) & 1;
        const int kt = idx >> 6;
        const int row = (r & 3) + 8 * (r >> 2) + 4 * hb + blk * 32;
        sBias[idx] = ((sBits[kt] >> row) & 1ull) ? -16384.0f : 0.0f;
    }

    // Q fragments (B-operand of 32x32x16): B[n=lane&31][k=hh*8+j]
    bf16x8 qf[4];
    {
        const unsigned short* qrow =
            q + ((size_t)(q0w + n31) * 4 + b) * 1024 + h * 64 + hh * 8;
#pragma unroll
        for (int kc = 0; kc < 4; ++kc) {
            B8 tmp;
            tmp.s = *(const short8*)(qrow + kc * 16);
            qf[kc] = tmp.b;
        }
    }

    f32x16 O0 = {}, O1 = {}, L = {};
    B4 ones;
#pragma unroll
    for (int j = 0; j < 4; ++j) ones.u[j] = 0x3F80;  // bf16 1.0
#if !defined(HAVE_X8)
    B8 ones8;
#pragma unroll
    for (int j = 0; j < 8; ++j) ones8.u[j] = 0x3F80;
#endif

    const unsigned short* kbase = k + (size_t)b * 1024 + h * 64;
    const unsigned short* vbase = v + (size_t)b * 1024 + h * 64;

    // prologue: stage tile 0 into buffer 0
    {
        const unsigned short* kr = kbase + (size_t)srow * 4096 + sseg * 8;
        short8 ka = *(const short8*)kr;
        short8 kb2 = *(const short8*)(kr + (size_t)32 * 4096);
        const unsigned short* vr = vbase + (size_t)srow * 4096 + sseg * 8;
        B8 va, vb2;
        va.s = *(const short8*)vr;
        vb2.s = *(const short8*)(vr + (size_t)32 * 4096);
        *(short8*)&sK[0][srow * TP + sseg * 8] = ka;
        *(short8*)&sK[0][(32 + srow) * TP + sseg * 8] = kb2;
#pragma unroll
        for (int s = 0; s < 8; ++s) {
            const int j = (s + srow + sseg) & 7;
            sVt[0][(sseg * 8 + j) * TP + srow] = va.u[j];
            sVt[0][(sseg * 8 + j) * TP + 32 + srow] = vb2.u[j];
        }
    }

#pragma unroll 2
    for (int kt = 0; kt < 16; ++kt) {
        const int cur = kt & 1;
        __syncthreads();
        // issue next tile's global loads (completion awaited at ds_write below)
        short8 nka, nkb;
        B8 nva, nvb;
        if (kt < 15) {
            const int k0n = (kt + 1) * 64;
            const unsigned short* kr = kbase + (size_t)(k0n + srow) * 4096 + sseg * 8;
            nka = *(const short8*)kr;
            nkb = *(const short8*)(kr + (size_t)32 * 4096);
            const unsigned short* vr = vbase + (size_t)(k0n + srow) * 4096 + sseg * 8;
            nva.s = *(const short8*)vr;
            nvb.s = *(const short8*)(vr + (size_t)32 * 4096);
        }
        // --- S^T = K·Q^T with mask-bias accumulator init; exp2; pack bf16 ---
        B4 pfr[2][4];
#pragma unroll
        for (int blk = 0; blk < 2; ++blk) {
            f32x16 c;
            const f32x4* bp = (const f32x4*)&sBias[((kt * 2 + blk) * 2 + hh) * 16];
#pragma unroll
            for (int i = 0; i < 4; ++i) {
                f32x4 x = bp[i];
#pragma unroll
                for (int j = 0; j < 4; ++j) c[i * 4 + j] = x[j];
            }
#pragma unroll
            for (int kc = 0; kc < 4; ++kc) {
                B8 af;
                af.s = *(const short8*)&sK[cur][(blk * 32 + n31) * TP + kc * 16 + hh * 8];
                c = __builtin_amdgcn_mfma_f32_32x32x16_bf16(af.b, qf[kc], c, 0, 0, 0);
            }
#pragma unroll
            for (int g = 0; g < 4; ++g)
#pragma unroll
                for (int j = 0; j < 4; ++j)
                    pfr[blk][g].b[j] = (__bf16)EXP2(c[g * 4 + j]);
        }
        // --- O += P·V, l += P·1 ---
#if defined(HAVE_X8)
#pragma unroll
        for (int blk = 0; blk < 2; ++blk) {
#pragma unroll
            for (int g = 0; g < 4; ++g) {
                const int sko = blk * 32 + g * 8 + hh * 4;
                B4 b0, b1;
                b0.s = *(const short4_*)&sVt[cur][n31 * TP + sko];
                b1.s = *(const short4_*)&sVt[cur][(32 + n31) * TP + sko];
                O0 = __builtin_amdgcn_mfma_f32_32x32x8bf16_1k(pfr[blk][g].s, b0.s, O0, 0, 0, 0);
                O1 = __builtin_amdgcn_mfma_f32_32x32x8bf16_1k(pfr[blk][g].s, b1.s, O1, 0, 0, 0);
                L = __builtin_amdgcn_mfma_f32_32x32x8bf16_1k(pfr[blk][g].s, ones.s, L, 0, 0, 0);
            }
        }
#else
#pragma unroll
        for (int blk = 0; blk < 2; ++blk) {
            B4 par[4];
#pragma unroll
            for (int g = 0; g < 4; ++g) {
                par[g].i[0] = __shfl_xor(pfr[blk][g].i[0], 32);
                par[g].i[1] = __shfl_xor(pfr[blk][g].i[1], 32);
            }
#pragma unroll
            for (int w = 0; w < 2; ++w) {
                const int gsel = 2 * w + hh;
                B4 lo = (hh == 0) ? pfr[blk][gsel] : par[gsel];
                B4 hi = (hh == 0) ? par[gsel] : pfr[blk][gsel];
                B8 afr;
#pragma unroll
                for (int j = 0; j < 4; ++j) {
                    afr.u[j] = lo.u[j];
                    afr.u[4 + j] = hi.u[j];
                }
                const int sko = blk * 32 + w * 16 + hh * 8;
                B8 b0, b1;
                b0.s = *(const short8*)&sVt[cur][n31 * TP + sko];
                b1.s = *(const short8*)&sVt[cur][(32 + n31) * TP + sko];
                O0 = __builtin_amdgcn_mfma_f32_32x32x16_bf16(afr.b, b0.b, O0, 0, 0, 0);
                O1 = __builtin_amdgcn_mfma_f32_32x32x16_bf16(afr.b, b1.b, O1, 0, 0, 0);
                L = __builtin_amdgcn_mfma_f32_32x32x16_bf16(afr.b, ones8.b, L, 0, 0, 0);
            }
        }
#endif
        // --- write next tile into the other buffer (vmcnt waited here) ---
        if (kt < 15) {
            const int nb = 1 - cur;
            *(short8*)&sK[nb][srow * TP + sseg * 8] = nka;
            *(short8*)&sK[nb][(32 + srow) * TP + sseg * 8] = nkb;
#pragma unroll
            for (int s = 0; s < 8; ++s) {
                const int j = (s + srow + sseg) & 7;
                sVt[nb][(sseg * 8 + j) * TP + srow] = nva.u[j];
                sVt[nb][(sseg * 8 + j) * TP + 32 + srow] = nvb.u[j];
            }
        }
    }

    // --- epilogue: rows q=(r&3)+8*(r>>2)+4*hh; l from ones-MFMA (per-lane) ---
    unsigned short* obase = o + ((size_t)q0w * 4 + b) * 1024 + h * 64 + n31;
#pragma unroll
    for (int r = 0; r < 16; ++r) {
        const int qr = (r & 3) + 8 * (r >> 2) + 4 * hh;
        const float inv = RCP(L[r]);
        obase[(size_t)qr * 4096] = f2bf_rne(O0[r] * inv);
        obase[(size_t)qr * 4096 + 32] = f2bf_rne(O1[r] * inv);
    }
}

extern "C" void kernel_launch(void* const* d_in, const int* in_sizes, int n_in,
                              void* d_out, int out_size, void* d_ws, size_t ws_size,
                              hipStream_t stream) {
    const float* query = (const float*)d_in[0];
    const float* key_ = (const float*)d_in[1];
    const float* value = (const float*)d_in[2];
    const int* key_mask = (const int*)d_in[3];
    const float* Wq = (const float*)d_in[4];
    const float* bq = (const float*)d_in[5];
    const float* Wk = (const float*)d_in[6];
    const float* bk = (const float*)d_in[7];
    const float* Wv = (const float*)d_in[8];
    const float* bv = (const float*)d_in[9];
    const float* Wo = (const float*)d_in[10];
    const float* bo = (const float*)d_in[11];
    float* out = (float*)d_out;

    const size_t NE = (size_t)4096 * 1024;
    unsigned short* q_ws = (unsigned short*)d_ws;
    unsigned short* k_ws = q_ws + NE;
    unsigned short* v_ws = k_ws + NE;
    unsigned short* a_ws = v_ws + NE;
    unsigned short* wt_ws = a_ws + NE;

    transpose_w<<<dim3(16, 16, 4), 256, 0, stream>>>(Wq, Wk, Wv, Wo, wt_ws);
    qkv_gemm<<<dim3(32, 8, 3), 256, 0, stream>>>(query, key_, value, wt_ws,
                                                 bq, bk, bv, q_ws, k_ws, v_ws);
    attn_kernel<<<dim3(8, 4, 16), 256, 0, stream>>>(q_ws, k_ws, v_ws, key_mask, a_ws);
    out_gemm<<<dim3(32, 8, 1), 256, 0, stream>>>(a_ws, wt_ws, bo, out);
}

// Round 6
// 251.998 us; speedup vs baseline: 1.0394x; 1.0394x over previous
//
#include <hip/hip_runtime.h>
#include <hip/hip_bf16.h>

// MultiHeadAttention S=1024 B=4 D=1024 H=16 DH=64
// [0] prep: Wq/Wk/Wv/Wo f32 -> bf16 B^T[n][k]  (z=0..3)
//          query/key/value f32 -> bf16 row-major (z=4..15)
//          qA -> ws attn_out region (dead until attn); kA,vA -> d_out scratch.
// [1] qkv_gemm: pure-m97 128x128 GEMM, BOTH operands via global_load_lds.
//     Grid (row fastest) pins same-A-strip blocks to one XCD (r5: FETCH 200->49MB).
// [2] attn: flash-style, dbuf LDS, mask via accumulator-init bias.
// [3] out_gemm.
// ws (bf16 elems): q @0, k @NE, v @2NE, attn_out/qA @3NE, WT(4x1M) @4NE (40MB)

typedef __attribute__((ext_vector_type(8))) short short8;
typedef __attribute__((ext_vector_type(4))) short short4_;
typedef __attribute__((ext_vector_type(4))) float f32x4;
typedef __attribute__((ext_vector_type(16))) float f32x16;
typedef __attribute__((ext_vector_type(8))) __bf16 bf16x8;
typedef __attribute__((ext_vector_type(4))) __bf16 bf16x4;

union B8 {
    short8 s;
    bf16x8 b;
    unsigned short u[8];
};
union B4 {
    short4_ s;
    bf16x4 b;
    unsigned short u[4];
    int i[2];
};

#if __has_builtin(__builtin_amdgcn_exp2f)
#define EXP2(x) __builtin_amdgcn_exp2f(x)
#else
#define EXP2(x) exp2f(x)
#endif
#if __has_builtin(__builtin_amdgcn_rcpf)
#define RCP(x) __builtin_amdgcn_rcpf(x)
#else
#define RCP(x) (1.0f / (x))
#endif

static __device__ __forceinline__ unsigned short f2bf_rne(float f) {
    union { float f; unsigned u; } v; v.f = f;
    unsigned r = v.u + 0x7FFFu + ((v.u >> 16) & 1u);
    return (unsigned short)(r >> 16);
}

static __device__ __forceinline__ void async_lds16(const void* g, const void* l) {
    __builtin_amdgcn_global_load_lds(
        (const __attribute__((address_space(1))) unsigned int*)(unsigned long long)g,
        (__attribute__((address_space(3))) unsigned int*)(unsigned int)(unsigned long long)l,
        16, 0, 0);
}

// ---------------------------------------------------------------------------
// Prep: z<4 weight transpose+convert; z>=4 activation f32->bf16 convert.
// ---------------------------------------------------------------------------
__global__ __launch_bounds__(256) void prep(
    const float* __restrict__ Wq, const float* __restrict__ Wk,
    const float* __restrict__ Wv, const float* __restrict__ Wo,
    const float* __restrict__ query, const float* __restrict__ key,
    const float* __restrict__ value,
    unsigned short* __restrict__ WT,
    unsigned short* __restrict__ qA, unsigned short* __restrict__ kA,
    unsigned short* __restrict__ vA) {
    const int t = threadIdx.x;
    const int z = blockIdx.z;

    if (z >= 4) {
        // activation convert: 12 slices x 1M elems; 256 blocks x 4096 elems.
        const int zz = z - 4;
        const int tensor = zz >> 2;
        const int part = zz & 3;
        const float* src = (tensor == 0) ? query : (tensor == 1) ? key : value;
        unsigned short* dst = (tensor == 0) ? qA : (tensor == 1) ? kA : vA;
        const int blk = blockIdx.y * 16 + blockIdx.x;
        const size_t base = (size_t)part * 1048576 + (size_t)blk * 4096 + t * 16;
        B8 w0, w1;
#pragma unroll
        for (int i = 0; i < 2; ++i) {
            f32x4 a = *(const f32x4*)(src + base + i * 8);
            f32x4 b = *(const f32x4*)(src + base + i * 8 + 4);
#pragma unroll
            for (int j = 0; j < 4; ++j) {
                (i ? w1 : w0).u[j] = f2bf_rne(a[j]);
                (i ? w1 : w0).u[4 + j] = f2bf_rne(b[j]);
            }
        }
        *(short8*)(dst + base) = w0.s;
        *(short8*)(dst + base + 8) = w1.s;
        return;
    }

    __shared__ float sT[64][65];
    const int dtile = blockIdx.x;
    const int sub = blockIdx.y;
    const float* src;
    int spitch;
    unsigned short* dst;
    if (z < 3) {
        const float* W = (z == 0) ? Wq : (z == 1) ? Wk : Wv;
        src = W + (size_t)sub * 65536 + (size_t)dtile * 64 * 64;
        spitch = 64;
        dst = WT + (size_t)z * 1048576 + (size_t)(sub * 64) * 1024 + dtile * 64;
    } else {
        src = Wo + (size_t)dtile * 64 * 1024 + sub * 64;
        spitch = 1024;
        dst = WT + (size_t)3 * 1048576 + (size_t)(sub * 64) * 1024 + dtile * 64;
    }

    const int r = t >> 2;
    const int cseg = (t & 3) * 16;
#pragma unroll
    for (int i = 0; i < 4; ++i) {
        f32x4 v = *(const f32x4*)(src + (size_t)r * spitch + cseg + i * 4);
#pragma unroll
        for (int j = 0; j < 4; ++j) sT[r][cseg + i * 4 + j] = v[j];
    }
    __syncthreads();
    B8 w0, w1;
#pragma unroll
    for (int i = 0; i < 8; ++i) {
        w0.u[i] = f2bf_rne(sT[cseg + i][r]);
        w1.u[i] = f2bf_rne(sT[cseg + 8 + i][r]);
    }
    *(short8*)(dst + (size_t)r * 1024 + cseg) = w0.s;
    *(short8*)(dst + (size_t)r * 1024 + cseg + 8) = w1.s;
}

// ---------------------------------------------------------------------------
// 128x128-tile GEMM (BK=64), both operands bf16 via global_load_lds (m97 shape).
// blockIdx.x = row-tile (fastest -> XCD pinning), blockIdx.y = col-tile.
// ---------------------------------------------------------------------------
template <bool OUT_F32>
__device__ __forceinline__ void gemm128(const unsigned short* __restrict__ A,
                                        const unsigned short* __restrict__ Bt,
                                        const float* __restrict__ bias,
                                        void* __restrict__ Cv, float oscale) {
    __shared__ unsigned short sA[128 * 64];
    __shared__ unsigned short sB[128 * 64];
    const int t = threadIdx.x;
    const int w = t >> 6;
    const int lane = t & 63;
    const int quad = lane >> 4;
    const int l15 = lane & 15;
    const int wr = w >> 1;
    const int wc = w & 1;
    const int row0 = blockIdx.x * 128;
    const int col0 = blockIdx.y * 128;
    const int lrow8 = lane >> 3;
    const int lseg = lane & 7;

    f32x4 acc[4][4] = {};

    for (int k0 = 0; k0 < 1024; k0 += 64) {
#pragma unroll
        for (int i = 0; i < 4; ++i) {
            const int rr = w * 32 + i * 8;
            async_lds16(A + (size_t)(row0 + rr + lrow8) * 1024 + k0 + lseg * 8,
                        &sA[rr * 64]);
            async_lds16(Bt + (size_t)(col0 + rr + lrow8) * 1024 + k0 + lseg * 8,
                        &sB[rr * 64]);
        }
        __syncthreads();
#pragma unroll
        for (int kf = 0; kf < 2; ++kf) {
            B8 af[4], bf[4];
#pragma unroll
            for (int i = 0; i < 4; ++i)
                af[i].s = *(const short8*)&sA[(wr * 64 + i * 16 + l15) * 64 + kf * 32 + quad * 8];
#pragma unroll
            for (int j = 0; j < 4; ++j)
                bf[j].s = *(const short8*)&sB[(wc * 64 + j * 16 + l15) * 64 + kf * 32 + quad * 8];
#pragma unroll
            for (int i = 0; i < 4; ++i)
#pragma unroll
                for (int j = 0; j < 4; ++j)
                    acc[i][j] = __builtin_amdgcn_mfma_f32_16x16x32_bf16(af[i].b, bf[j].b,
                                                                        acc[i][j], 0, 0, 0);
        }
        __syncthreads();
    }
#pragma unroll
    for (int j = 0; j < 4; ++j) {
        const int col = col0 + wc * 64 + j * 16 + l15;
        const float bb = bias[col];
#pragma unroll
        for (int i = 0; i < 4; ++i) {
#pragma unroll
            for (int r = 0; r < 4; ++r) {
                const int row = row0 + wr * 64 + i * 16 + quad * 4 + r;
                const size_t idx = (size_t)row * 1024 + col;
                const float val = (acc[i][j][r] + bb) * oscale;
                if constexpr (OUT_F32)
                    ((float*)Cv)[idx] = val;
                else
                    ((unsigned short*)Cv)[idx] = f2bf_rne(val);
            }
        }
    }
}

#define SCALE_L2E 0.18033688011112042f  // (1/8) * log2(e)

__global__ __launch_bounds__(256) void qkv_gemm(
    const unsigned short* __restrict__ qA, const unsigned short* __restrict__ kA,
    const unsigned short* __restrict__ vA,
    const unsigned short* __restrict__ WT,
    const float* __restrict__ bq, const float* __restrict__ bk, const float* __restrict__ bv,
    unsigned short* q_o, unsigned short* k_o, unsigned short* v_o) {
    const int p = blockIdx.z;
    const unsigned short* A = (p == 0) ? qA : (p == 1) ? kA : vA;
    const unsigned short* Bt = WT + (size_t)p * 1048576;
    const float* bias = (p == 0) ? bq : (p == 1) ? bk : bv;
    unsigned short* C = (p == 0) ? q_o : (p == 1) ? k_o : v_o;
    const float osc = (p == 0) ? SCALE_L2E : 1.0f;  // pre-scale q for attn exp2
    gemm128<false>(A, Bt, bias, C, osc);
}

__global__ __launch_bounds__(256) void out_gemm(const unsigned short* __restrict__ A,
                                                const unsigned short* __restrict__ WT,
                                                const float* __restrict__ bo,
                                                float* __restrict__ C) {
    gemm128<true>(A, WT + (size_t)3 * 1048576, bo, C, 1.0f);
}

// ---------------------------------------------------------------------------
// Flash-style attention, double-buffered LDS, 1 sync per k-tile.
// ---------------------------------------------------------------------------
#define TP 72

#if __has_builtin(__builtin_amdgcn_mfma_f32_32x32x8bf16_1k)
#define HAVE_X8 1
#endif

__global__ __launch_bounds__(256) void attn_kernel(
    const unsigned short* __restrict__ q,   // pre-scaled by log2(e)/8
    const unsigned short* __restrict__ k,
    const unsigned short* __restrict__ v,
    const int* __restrict__ key_mask,
    unsigned short* __restrict__ o) {
    __shared__ unsigned short sK[2][64 * TP];
    __shared__ unsigned short sVt[2][64 * TP];
    __shared__ float sBias[2048];  // [kt][blk][hh][r]
    __shared__ unsigned long long sBits[16];

    const int t = threadIdx.x;
    const int wave = t >> 6;
    const int lane = t & 63;
    const int n31 = lane & 31;
    const int hh = lane >> 5;
    const int b = blockIdx.y;
    const int h = blockIdx.z;
    const int q0w = blockIdx.x * 128 + wave * 32;
    const int srow = t >> 3;  // 0..31
    const int sseg = t & 7;   // 0..7

    // mask bits: bit set => masked out
#pragma unroll
    for (int i = 0; i < 4; ++i) {
        const int idx = i * 4 + wave;
        const int sk = idx * 64 + lane;
        unsigned long long bal = __ballot(key_mask[sk * 4 + b] != 0);
        if (lane == 0) sBits[idx] = bal;
    }
    __syncthreads();
    // accumulator-init bias table: -16384 => exp2 underflow => exact 0
#pragma unroll
    for (int i = 0; i < 8; ++i) {
        const int idx = t * 8 + i;
        const int r = idx & 15;
        const int hb = (idx >> 4) & 1;
        const int blk = (idx >> 5) & 1;
        const int kt = idx >> 6;
        const int row = (r & 3) + 8 * (r >> 2) + 4 * hb + blk * 32;
        sBias[idx] = ((sBits[kt] >> row) & 1ull) ? -16384.0f : 0.0f;
    }

    // Q fragments (B-operand of 32x32x16): B[n=lane&31][k=hh*8+j]
    bf16x8 qf[4];
    {
        const unsigned short* qrow =
            q + ((size_t)(q0w + n31) * 4 + b) * 1024 + h * 64 + hh * 8;
#pragma unroll
        for (int kc = 0; kc < 4; ++kc) {
            B8 tmp;
            tmp.s = *(const short8*)(qrow + kc * 16);
            qf[kc] = tmp.b;
        }
    }

    f32x16 O0 = {}, O1 = {}, L = {};
    B4 ones;
#pragma unroll
    for (int j = 0; j < 4; ++j) ones.u[j] = 0x3F80;  // bf16 1.0
#if !defined(HAVE_X8)
    B8 ones8;
#pragma unroll
    for (int j = 0; j < 8; ++j) ones8.u[j] = 0x3F80;
#endif

    const unsigned short* kbase = k + (size_t)b * 1024 + h * 64;
    const unsigned short* vbase = v + (size_t)b * 1024 + h * 64;

    // prologue: stage tile 0 into buffer 0
    {
        const unsigned short* kr = kbase + (size_t)srow * 4096 + sseg * 8;
        short8 ka = *(const short8*)kr;
        short8 kb2 = *(const short8*)(kr + (size_t)32 * 4096);
        const unsigned short* vr = vbase + (size_t)srow * 4096 + sseg * 8;
        B8 va, vb2;
        va.s = *(const short8*)vr;
        vb2.s = *(const short8*)(vr + (size_t)32 * 4096);
        *(short8*)&sK[0][srow * TP + sseg * 8] = ka;
        *(short8*)&sK[0][(32 + srow) * TP + sseg * 8] = kb2;
#pragma unroll
        for (int s = 0; s < 8; ++s) {
            const int j = (s + srow + sseg) & 7;
            sVt[0][(sseg * 8 + j) * TP + srow] = va.u[j];
            sVt[0][(sseg * 8 + j) * TP + 32 + srow] = vb2.u[j];
        }
    }

#pragma unroll 2
    for (int kt = 0; kt < 16; ++kt) {
        const int cur = kt & 1;
        __syncthreads();
        // issue next tile's global loads (completion awaited at ds_write below)
        short8 nka, nkb;
        B8 nva, nvb;
        if (kt < 15) {
            const int k0n = (kt + 1) * 64;
            const unsigned short* kr = kbase + (size_t)(k0n + srow) * 4096 + sseg * 8;
            nka = *(const short8*)kr;
            nkb = *(const short8*)(kr + (size_t)32 * 4096);
            const unsigned short* vr = vbase + (size_t)(k0n + srow) * 4096 + sseg * 8;
            nva.s = *(const short8*)vr;
            nvb.s = *(const short8*)(vr + (size_t)32 * 4096);
        }
        // --- S^T = K·Q^T with mask-bias accumulator init; exp2; pack bf16 ---
        B4 pfr[2][4];
#pragma unroll
        for (int blk = 0; blk < 2; ++blk) {
            f32x16 c;
            const f32x4* bp = (const f32x4*)&sBias[((kt * 2 + blk) * 2 + hh) * 16];
#pragma unroll
            for (int i = 0; i < 4; ++i) {
                f32x4 x = bp[i];
#pragma unroll
                for (int j = 0; j < 4; ++j) c[i * 4 + j] = x[j];
            }
#pragma unroll
            for (int kc = 0; kc < 4; ++kc) {
                B8 af;
                af.s = *(const short8*)&sK[cur][(blk * 32 + n31) * TP + kc * 16 + hh * 8];
                c = __builtin_amdgcn_mfma_f32_32x32x16_bf16(af.b, qf[kc], c, 0, 0, 0);
            }
#pragma unroll
            for (int g = 0; g < 4; ++g)
#pragma unroll
                for (int j = 0; j < 4; ++j)
                    pfr[blk][g].b[j] = (__bf16)EXP2(c[g * 4 + j]);
        }
        // --- O += P·V, l += P·1 ---
#if defined(HAVE_X8)
#pragma unroll
        for (int blk = 0; blk < 2; ++blk) {
#pragma unroll
            for (int g = 0; g < 4; ++g) {
                const int sko = blk * 32 + g * 8 + hh * 4;
                B4 b0, b1;
                b0.s = *(const short4_*)&sVt[cur][n31 * TP + sko];
                b1.s = *(const short4_*)&sVt[cur][(32 + n31) * TP + sko];
                O0 = __builtin_amdgcn_mfma_f32_32x32x8bf16_1k(pfr[blk][g].s, b0.s, O0, 0, 0, 0);
                O1 = __builtin_amdgcn_mfma_f32_32x32x8bf16_1k(pfr[blk][g].s, b1.s, O1, 0, 0, 0);
                L = __builtin_amdgcn_mfma_f32_32x32x8bf16_1k(pfr[blk][g].s, ones.s, L, 0, 0, 0);
            }
        }
#else
#pragma unroll
        for (int blk = 0; blk < 2; ++blk) {
            B4 par[4];
#pragma unroll
            for (int g = 0; g < 4; ++g) {
                par[g].i[0] = __shfl_xor(pfr[blk][g].i[0], 32);
                par[g].i[1] = __shfl_xor(pfr[blk][g].i[1], 32);
            }
#pragma unroll
            for (int w = 0; w < 2; ++w) {
                const int gsel = 2 * w + hh;
                B4 lo = (hh == 0) ? pfr[blk][gsel] : par[gsel];
                B4 hi = (hh == 0) ? par[gsel] : pfr[blk][gsel];
                B8 afr;
#pragma unroll
                for (int j = 0; j < 4; ++j) {
                    afr.u[j] = lo.u[j];
                    afr.u[4 + j] = hi.u[j];
                }
                const int sko = blk * 32 + w * 16 + hh * 8;
                B8 b0, b1;
                b0.s = *(const short8*)&sVt[cur][n31 * TP + sko];
                b1.s = *(const short8*)&sVt[cur][(32 + n31) * TP + sko];
                O0 = __builtin_amdgcn_mfma_f32_32x32x16_bf16(afr.b, b0.b, O0, 0, 0, 0);
                O1 = __builtin_amdgcn_mfma_f32_32x32x16_bf16(afr.b, b1.b, O1, 0, 0, 0);
                L = __builtin_amdgcn_mfma_f32_32x32x16_bf16(afr.b, ones8.b, L, 0, 0, 0);
            }
        }
#endif
        // --- write next tile into the other buffer (vmcnt waited here) ---
        if (kt < 15) {
            const int nb = 1 - cur;
            *(short8*)&sK[nb][srow * TP + sseg * 8] = nka;
            *(short8*)&sK[nb][(32 + srow) * TP + sseg * 8] = nkb;
#pragma unroll
            for (int s = 0; s < 8; ++s) {
                const int j = (s + srow + sseg) & 7;
                sVt[nb][(sseg * 8 + j) * TP + srow] = nva.u[j];
                sVt[nb][(sseg * 8 + j) * TP + 32 + srow] = nvb.u[j];
            }
        }
    }

    // --- epilogue: rows q=(r&3)+8*(r>>2)+4*hh; l from ones-MFMA (per-lane) ---
    unsigned short* obase = o + ((size_t)q0w * 4 + b) * 1024 + h * 64 + n31;
#pragma unroll
    for (int r = 0; r < 16; ++r) {
        const int qr = (r & 3) + 8 * (r >> 2) + 4 * hh;
        const float inv = RCP(L[r]);
        obase[(size_t)qr * 4096] = f2bf_rne(O0[r] * inv);
        obase[(size_t)qr * 4096 + 32] = f2bf_rne(O1[r] * inv);
    }
}

extern "C" void kernel_launch(void* const* d_in, const int* in_sizes, int n_in,
                              void* d_out, int out_size, void* d_ws, size_t ws_size,
                              hipStream_t stream) {
    const float* query = (const float*)d_in[0];
    const float* key_ = (const float*)d_in[1];
    const float* value = (const float*)d_in[2];
    const int* key_mask = (const int*)d_in[3];
    const float* Wq = (const float*)d_in[4];
    const float* bq = (const float*)d_in[5];
    const float* Wk = (const float*)d_in[6];
    const float* bk = (const float*)d_in[7];
    const float* Wv = (const float*)d_in[8];
    const float* bv = (const float*)d_in[9];
    const float* Wo = (const float*)d_in[10];
    const float* bo = (const float*)d_in[11];
    float* out = (float*)d_out;

    const size_t NE = (size_t)4096 * 1024;
    unsigned short* q_ws = (unsigned short*)d_ws;
    unsigned short* k_ws = q_ws + NE;
    unsigned short* v_ws = k_ws + NE;
    unsigned short* a_ws = v_ws + NE;   // attn output; doubles as qA before attn
    unsigned short* wt_ws = a_ws + NE;  // 4 x 1M bf16 weights

    // activation bf16 scratch: qA in a_ws (dead until attn writes it);
    // kA/vA in d_out (dead until out_gemm writes it; 16MB = 2 x 8MB).
    unsigned short* qA = a_ws;
    unsigned short* kA = (unsigned short*)d_out;
    unsigned short* vA = kA + NE;

    prep<<<dim3(16, 16, 16), 256, 0, stream>>>(Wq, Wk, Wv, Wo, query, key_, value,
                                               wt_ws, qA, kA, vA);
    qkv_gemm<<<dim3(32, 8, 3), 256, 0, stream>>>(qA, kA, vA, wt_ws,
                                                 bq, bk, bv, q_ws, k_ws, v_ws);
    attn_kernel<<<dim3(8, 4, 16), 256, 0, stream>>>(q_ws, k_ws, v_ws, key_mask, a_ws);
    out_gemm<<<dim3(32, 8, 1), 256, 0, stream>>>(a_ws, wt_ws, bo, out);
}